// Round 5
// baseline (462.297 us; speedup 1.0000x reference)
//
#include <hip/hip_runtime.h>

#define AW 264   // bf16 elems per activation LDS row (256 + 8 pad)

typedef __attribute__((ext_vector_type(8))) short bf16x8;
typedef __attribute__((ext_vector_type(4))) float f32x4;

__device__ __forceinline__ unsigned short f2bf(float f) {
    unsigned u = __float_as_uint(f);
    u += 0x7fffu + ((u >> 16) & 1u);          // RNE to bf16
    return (unsigned short)(u >> 16);
}
__device__ __forceinline__ float bf2f(unsigned short h) {
    return __uint_as_float(((unsigned)h) << 16);
}
// 5-op tanh: 1 - 2/(e^{2x}+1). Safe at +/-inf. |err| ~1e-7.
__device__ __forceinline__ float fast_tanh(float x) {
    float e = __expf(2.0f * x);
    return 1.0f - 2.0f / (e + 1.0f);
}
// Workgroup barrier ordering LDS only — does NOT drain vmcnt, so global
// loads issued before it stay in flight across it.
__device__ __forceinline__ void bar_lds() {
    asm volatile("s_waitcnt lgkmcnt(0)\n\ts_barrier" ::: "memory");
}

// ---------------- fused precompute: weights -> MFMA B-frag layout, hi/lo bf16 ----
// F layout: [plane][nt][kc][lane(64)][j(8)]; value = W[n*K+k], n=nt*16+(l&15), k=kc*32+(l>>4)*8+j
__global__ __launch_bounds__(256) void pk_all(
    const float* __restrict__ Wvf1, const float* __restrict__ Wvf2,
    const float* __restrict__ Wm,   const float* __restrict__ bm,
    const float* __restrict__ logsig,
    unsigned short* __restrict__ W1F, unsigned short* __restrict__ W2F,
    unsigned short* __restrict__ A3F, float* __restrict__ c_all)
{
    __shared__ float ls[32][62];
    const int b = blockIdx.x, t = threadIdx.x;
    if (b < 128) {                      // W1: N=256 x K=128, KC=4
        int u = b * 256 + t;            // 32768 total
        int j = u & 7, l = (u >> 3) & 63;
        int kc = (u >> 9) & 3, nt = (u >> 9) >> 2;
        int n = nt * 16 + (l & 15), k = kc * 32 + (l >> 4) * 8 + j;
        float w = Wvf1[n * 128 + k];
        unsigned short hi = f2bf(w);
        W1F[u] = hi;
        W1F[32768 + u] = f2bf(w - bf2f(hi));
    } else if (b < 384) {               // W2: 256x256, KC=8
        int u = (b - 128) * 256 + t;    // 65536 total
        int j = u & 7, l = (u >> 3) & 63;
        int kc = (u >> 9) & 7, nt = (u >> 9) >> 3;
        int n = nt * 16 + (l & 15), k = kc * 32 + (l >> 4) * 8 + j;
        float w = Wvf2[n * 256 + k];
        unsigned short hi = f2bf(w);
        W2F[u] = hi;
        W2F[65536 + u] = f2bf(w - bf2f(hi));
    } else if (b < 512) {               // A_r[h,v] = sum_l Wm[(h*62+l)*256+v]*logsig[r,1+l]
        for (int e = t; e < 32 * 62; e += 256)
            ls[e / 62][e % 62] = logsig[(e / 62) * 63 + 1 + (e % 62)];
        __syncthreads();
        int u = (b - 384) * 256 + t;    // 32768 per r
        int j = u & 7, l = (u >> 3) & 63, kc = (u >> 9) & 7, nt = (u >> 12) & 7;
        int h = nt * 16 + (l & 15);
        int v = kc * 32 + (l >> 4) * 8 + j;
        float acc[32];
#pragma unroll
        for (int r = 0; r < 32; r++) acc[r] = 0.f;
        for (int ll = 0; ll < 62; ll++) {
            float wv = Wm[(h * 62 + ll) * 256 + v];
#pragma unroll
            for (int r = 0; r < 32; r++) acc[r] += wv * ls[r][ll];
        }
        for (int r = 0; r < 32; r++) {
            unsigned short hi = f2bf(acc[r]);
            A3F[r * 65536 + u] = hi;
            A3F[r * 65536 + 32768 + u] = f2bf(acc[r] - bf2f(hi));
        }
    } else {                            // c_r[h] = bm[h,:] . seg_r
        int u = (b - 512) * 256 + t;    // 4096 = [r(32)][h(128)]
        int r = u >> 7, h = u & 127;
        float acc = 0.f;
        for (int ll = 0; ll < 62; ll++) acc += bm[h * 62 + ll] * logsig[r * 63 + 1 + ll];
        c_all[u] = acc;
    }
}

// ---------------- main fused kernel: 32 blocks x 16 rows, 4 waves (1/SIMD), 20-step Heun --
// 256 threads -> ~512 VGPR/wave budget: W2 hi/lo RESIDENT in registers (256 VGPR),
// W1 hi/lo resident in LDS (128 KB), A_r streamed per-eval in two half-K windows
// (64 VGPR, issued before bar_lds so loads fly across the barrier). bf16 hi/lo
// 3-chain numerics (round-1/4 verified, absmax 0.0039). Y/K1 state in registers.
__global__ __launch_bounds__(256, 1) void rde_main(
    const float* __restrict__ ts, const float* __restrict__ x0,
    const float* __restrict__ intervals,
    const float* __restrict__ b1g, const float* __restrict__ b2g,
    const float* __restrict__ Win, const float* __restrict__ bin,
    const float* __restrict__ Wout, const float* __restrict__ bout,
    const unsigned short* __restrict__ W1F, const unsigned short* __restrict__ W2F,
    const unsigned short* __restrict__ A3F, const float* __restrict__ c_all,
    float* __restrict__ out)
{
    __shared__ __align__(16) unsigned short W1s[65536];           // 128 KB hi+lo
    __shared__ __align__(16) unsigned short AH[16 * AW];          // act hi (in-place)
    __shared__ __align__(16) unsigned short AL[16 * AW];          // act lo
    __shared__ float ivl[33];
    __shared__ int   r_arr[40];
    __shared__ float s_arr[40];
    __shared__ float lg[16][12];

    const int t    = threadIdx.x;
    const int lane = t & 63;
    const int wv   = t >> 6;        // wave 0..3
    const int m16  = lane & 15;
    const int q    = lane >> 4;
    const int row0 = blockIdx.x * 16;

    if (t < 33) ivl[t] = intervals[t];
    // W1 hi+lo -> LDS (once): 65536 halfs = 8192 uint4
    for (int e = t; e < 8192; e += 256)
        ((uint4*)W1s)[e] = ((const uint4*)W1F)[e];
    __syncthreads();

    const float ts0 = ts[0];
    const float dt  = __fdiv_rn(ts[32] - ts0, 20.0f);   // bit-exact vs reference

    if (t < 40) {   // searchsorted idx + 1/delta for all 40 VF evals
        int i = t >> 1;
        float tv = ts0 + (float)i * dt;
        if (t & 1) tv += dt;
        int p = 0;
        for (int j2 = 0; j2 < 32; j2++) p += (ivl[1 + j2] < tv) ? 1 : 0;
        int idx = p + 1;
        idx = idx < 1 ? 1 : idx;
        idx = idx > 32 ? 32 : idx;
        r_arr[t] = idx - 1;
        s_arr[t] = __fdiv_rn(1.0f, ivl[idx] - ivl[idx - 1]);
    }

    // persistent W2 hi/lo fragments: wave wv owns n-tiles wv*4 .. wv*4+3 (256 VGPRs)
    bf16x8 w2h[4][8], w2l[4][8];
#pragma unroll
    for (int tt = 0; tt < 4; tt++)
#pragma unroll
        for (int kc = 0; kc < 8; kc++) {
            const unsigned short* bp = W2F + (((wv * 4 + tt) * 8 + kc) * 64 + lane) * 8;
            w2h[tt][kc] = *(const bf16x8*)bp;
            w2l[tt][kc] = *(const bf16x8*)(bp + 65536);
        }

    // biases preloaded once (stage1/2 init comes from regs, no loads in loop)
    float b1v[4], b2v[4];
#pragma unroll
    for (int tt = 0; tt < 4; tt++) {
        b1v[tt] = b1g[(wv * 4 + tt) * 16 + m16];
        b2v[tt] = b2g[(wv * 4 + tt) * 16 + m16];
    }

    // y0 = x0 @ Win.T + bin -> Y regs (stage3 C/D layout: row q*4+r, col (wv*2+tt)*16+m16)
    float Y[2][4], K1[2][4];
#pragma unroll
    for (int tt = 0; tt < 2; tt++)
#pragma unroll
        for (int r = 0; r < 4; r++) {
            int m = q * 4 + r, h = (wv * 2 + tt) * 16 + m16;
            float acc = bin[h];
            const float* xr = x0 + (row0 + m) * 5;
#pragma unroll
            for (int d = 0; d < 5; d++) acc += xr[d] * Win[h * 5 + d];
            Y[tt][r] = acc;
            K1[tt][r] = 0.f;
            unsigned short hi = f2bf(acc);
            AH[m * AW + h] = hi;
            AL[m * AW + h] = f2bf(acc - bf2f(hi));
        }
    __syncthreads();

#pragma unroll 1
    for (int i = 0; i < 20; i++) {
#pragma unroll
        for (int half = 0; half < 2; half++) {
            const int e  = 2 * i + half;
            const int ri = r_arr[e];
            const float s = s_arr[e];
            const unsigned short* ABase = A3F + ri * 65536;

            // ---- stage1: h1 = relu(y @ W1.T + b1), K=128 (KC=4), W1 from LDS ----
            f32x4 aA[4], aB[4], aC[4];
#pragma unroll
            for (int tt = 0; tt < 4; tt++) {
                aA[tt] = (f32x4){b1v[tt], b1v[tt], b1v[tt], b1v[tt]};
                aB[tt] = (f32x4){0.f, 0.f, 0.f, 0.f};
                aC[tt] = (f32x4){0.f, 0.f, 0.f, 0.f};
            }
#pragma unroll
            for (int kc = 0; kc < 4; kc++) {
                int ao = m16 * AW + kc * 32 + q * 8;
                bf16x8 ah = *(const bf16x8*)(AH + ao);
                bf16x8 al = *(const bf16x8*)(AL + ao);
#pragma unroll
                for (int tt = 0; tt < 4; tt++) {
                    int wb = (((wv * 4 + tt) * 4 + kc) * 64 + lane) * 8;
                    bf16x8 bh = *(const bf16x8*)(W1s + wb);
                    bf16x8 bl = *(const bf16x8*)(W1s + 32768 + wb);
                    aA[tt] = __builtin_amdgcn_mfma_f32_16x16x32_bf16(ah, bh, aA[tt], 0, 0, 0);
                    aB[tt] = __builtin_amdgcn_mfma_f32_16x16x32_bf16(ah, bl, aB[tt], 0, 0, 0);
                    aC[tt] = __builtin_amdgcn_mfma_f32_16x16x32_bf16(al, bh, aC[tt], 0, 0, 0);
                }
            }
            bar_lds();                              // all reads of y done
#pragma unroll
            for (int tt = 0; tt < 4; tt++) {        // commit h1 (hi/lo)
                int n = (wv * 4 + tt) * 16 + m16;
#pragma unroll
                for (int r = 0; r < 4; r++) {
                    int m = q * 4 + r;              // C/D: col=lane&15, row=(lane>>4)*4+reg
                    float v = fmaxf(aA[tt][r] + aB[tt][r] + aC[tt][r], 0.f);
                    unsigned short hi = f2bf(v);
                    AH[m * AW + n] = hi;
                    AL[m * AW + n] = f2bf(v - bf2f(hi));
                }
            }
            bar_lds();

            // ---- stage2: h2 = tanh(h1 @ W2.T + b2), K=256 (KC=8), W2 in regs ----
#pragma unroll
            for (int tt = 0; tt < 4; tt++) {
                aA[tt] = (f32x4){b2v[tt], b2v[tt], b2v[tt], b2v[tt]};
                aB[tt] = (f32x4){0.f, 0.f, 0.f, 0.f};
                aC[tt] = (f32x4){0.f, 0.f, 0.f, 0.f};
            }
#pragma unroll
            for (int kc = 0; kc < 8; kc++) {
                int ao = m16 * AW + kc * 32 + q * 8;
                bf16x8 ah = *(const bf16x8*)(AH + ao);
                bf16x8 al = *(const bf16x8*)(AL + ao);
#pragma unroll
                for (int tt = 0; tt < 4; tt++) {
                    aA[tt] = __builtin_amdgcn_mfma_f32_16x16x32_bf16(ah, w2h[tt][kc], aA[tt], 0, 0, 0);
                    aB[tt] = __builtin_amdgcn_mfma_f32_16x16x32_bf16(ah, w2l[tt][kc], aB[tt], 0, 0, 0);
                    aC[tt] = __builtin_amdgcn_mfma_f32_16x16x32_bf16(al, w2h[tt][kc], aC[tt], 0, 0, 0);
                }
            }
            bar_lds();
#pragma unroll
            for (int tt = 0; tt < 4; tt++) {        // commit h2 (hi/lo)
                int n = (wv * 4 + tt) * 16 + m16;
#pragma unroll
                for (int r = 0; r < 4; r++) {
                    int m = q * 4 + r;
                    float v = fast_tanh(aA[tt][r] + aB[tt][r] + aC[tt][r]);
                    unsigned short hi = f2bf(v);
                    AH[m * AW + n] = hi;
                    AL[m * AW + n] = f2bf(v - bf2f(hi));
                }
            }

            // ---- A_r half-0 prefetch + c_r: issued BEFORE the barrier so the
            //      loads are in flight across it (bar_lds doesn't drain vmcnt) ----
            bf16x8 afh[2][4], afl[2][4];
#pragma unroll
            for (int tt = 0; tt < 2; tt++)
#pragma unroll
                for (int kc = 0; kc < 4; kc++) {
                    const unsigned short* bp = ABase + (((wv * 2 + tt) * 8 + kc) * 64 + lane) * 8;
                    afh[tt][kc] = *(const bf16x8*)bp;
                    afl[tt][kc] = *(const bf16x8*)(bp + 32768);
                }
            float cv[2];
#pragma unroll
            for (int tt = 0; tt < 2; tt++)
                cv[tt] = c_all[ri * 128 + (wv * 2 + tt) * 16 + m16];
            bar_lds();

            // ---- stage3: k = (h2 @ A_r.T + c_r) * s, N=128, 2 n-tiles/wave ----
            f32x4 kA[2], kB[2], kC[2];
#pragma unroll
            for (int tt = 0; tt < 2; tt++) {
                kA[tt] = (f32x4){0.f, 0.f, 0.f, 0.f};
                kB[tt] = (f32x4){0.f, 0.f, 0.f, 0.f};
                kC[tt] = (f32x4){0.f, 0.f, 0.f, 0.f};
            }
#pragma unroll
            for (int kc = 0; kc < 4; kc++) {        // half 0 (kc 0..3)
                int ao = m16 * AW + kc * 32 + q * 8;
                bf16x8 ah = *(const bf16x8*)(AH + ao);
                bf16x8 al = *(const bf16x8*)(AL + ao);
#pragma unroll
                for (int tt = 0; tt < 2; tt++) {
                    kA[tt] = __builtin_amdgcn_mfma_f32_16x16x32_bf16(ah, afh[tt][kc], kA[tt], 0, 0, 0);
                    kB[tt] = __builtin_amdgcn_mfma_f32_16x16x32_bf16(ah, afl[tt][kc], kB[tt], 0, 0, 0);
                    kC[tt] = __builtin_amdgcn_mfma_f32_16x16x32_bf16(al, afh[tt][kc], kC[tt], 0, 0, 0);
                }
            }
#pragma unroll
            for (int tt = 0; tt < 2; tt++)          // half-1 fragment loads (reuse regs)
#pragma unroll
                for (int kc = 0; kc < 4; kc++) {
                    const unsigned short* bp = ABase + (((wv * 2 + tt) * 8 + 4 + kc) * 64 + lane) * 8;
                    afh[tt][kc] = *(const bf16x8*)bp;
                    afl[tt][kc] = *(const bf16x8*)(bp + 32768);
                }
#pragma unroll
            for (int kc = 0; kc < 4; kc++) {        // half 1 (kc 4..7)
                int ao = m16 * AW + (4 + kc) * 32 + q * 8;
                bf16x8 ah = *(const bf16x8*)(AH + ao);
                bf16x8 al = *(const bf16x8*)(AL + ao);
#pragma unroll
                for (int tt = 0; tt < 2; tt++) {
                    kA[tt] = __builtin_amdgcn_mfma_f32_16x16x32_bf16(ah, afh[tt][kc], kA[tt], 0, 0, 0);
                    kB[tt] = __builtin_amdgcn_mfma_f32_16x16x32_bf16(ah, afl[tt][kc], kB[tt], 0, 0, 0);
                    kC[tt] = __builtin_amdgcn_mfma_f32_16x16x32_bf16(al, afh[tt][kc], kC[tt], 0, 0, 0);
                }
            }
            bar_lds();                              // all reads of h2 done
#pragma unroll
            for (int tt = 0; tt < 2; tt++) {        // Heun commit + y -> act (hi/lo)
                int n = (wv * 2 + tt) * 16 + m16;   // h index
#pragma unroll
                for (int r = 0; r < 4; r++) {
                    int m = q * 4 + r;
                    float kv = (kA[tt][r] + kB[tt][r] + kC[tt][r] + cv[tt]) * s;
                    float yn;
                    if (half == 0) {                 // k1: stash, form y+dt*k1
                        K1[tt][r] = kv;
                        yn = Y[tt][r] + dt * kv;
                    } else {                         // k2: y += 0.5*dt*(k1+k2)
                        yn = Y[tt][r] + 0.5f * dt * (K1[tt][r] + kv);
                        Y[tt][r] = yn;
                    }
                    unsigned short hi = f2bf(yn);
                    AH[m * AW + n] = hi;
                    AL[m * AW + n] = f2bf(yn - bf2f(hi));
                }
            }
            bar_lds();
        }
    }

    // epilogue: Y regs -> LDS floats (reuse AH region: 16 x 132 f32 = 8448 B)
    float* Ys = (float*)AH;
#pragma unroll
    for (int tt = 0; tt < 2; tt++)
#pragma unroll
        for (int r = 0; r < 4; r++)
            Ys[(q * 4 + r) * 132 + (wv * 2 + tt) * 16 + m16] = Y[tt][r];
    __syncthreads();
    if (t < 160) {                  // logits
        int m = t / 10, c = t % 10;
        float acc = bout[c];
        for (int k = 0; k < 128; k++) acc += Ys[m * 132 + k] * Wout[c * 128 + k];
        lg[m][c] = acc;
    }
    __syncthreads();
    if (t < 16) {                   // softmax
        float mx = -1e30f;
#pragma unroll
        for (int c = 0; c < 10; c++) mx = fmaxf(mx, lg[t][c]);
        float ex[10], sum = 0.f;
#pragma unroll
        for (int c = 0; c < 10; c++) { ex[c] = expf(lg[t][c] - mx); sum += ex[c]; }
        float inv = __fdiv_rn(1.0f, sum);
#pragma unroll
        for (int c = 0; c < 10; c++) out[(row0 + t) * 10 + c] = ex[c] * inv;
    }
}

extern "C" void kernel_launch(void* const* d_in, const int* in_sizes, int n_in,
                              void* d_out, int out_size, void* d_ws, size_t ws_size,
                              hipStream_t stream) {
    const float* ts     = (const float*)d_in[0];
    const float* logsig = (const float*)d_in[1];
    const float* x0     = (const float*)d_in[2];
    const float* ivls   = (const float*)d_in[3];
    const float* Wvf1   = (const float*)d_in[4];
    const float* bvf1   = (const float*)d_in[5];
    const float* Wvf2   = (const float*)d_in[6];
    const float* bvf2   = (const float*)d_in[7];
    const float* Wm     = (const float*)d_in[8];
    const float* bm     = (const float*)d_in[9];
    const float* Win    = (const float*)d_in[10];
    const float* bin    = (const float*)d_in[11];
    const float* Wout   = (const float*)d_in[12];
    const float* bout   = (const float*)d_in[13];

    unsigned short* W1F = (unsigned short*)d_ws;        // 65536 ush (128KB, hi+lo)
    unsigned short* W2F = W1F + 65536;                  // 131072 ush (256KB, hi+lo)
    unsigned short* A3F = W2F + 131072;                 // 2097152 ush (4MB, 32 r's hi+lo)
    float* c_all = (float*)(A3F + 2097152);             // 4096 f32 (16KB)
    float* out = (float*)d_out;

    pk_all<<<dim3(528), dim3(256), 0, stream>>>(Wvf1, Wvf2, Wm, bm, logsig,
                                                W1F, W2F, A3F, c_all);
    rde_main<<<dim3(32), dim3(256), 0, stream>>>(
        ts, x0, ivls, bvf1, bvf2, Win, bin, Wout, bout,
        W1F, W2F, A3F, c_all, out);
}

// Round 7
// 299.576 us; speedup vs baseline: 1.5432x; 1.5432x over previous
//
#include <hip/hip_runtime.h>

#define AW 264   // fp16 elems per activation LDS row (256 + 8 pad)

typedef _Float16 f16x8 __attribute__((ext_vector_type(8)));
typedef __attribute__((ext_vector_type(4))) float f32x4;

// 5-op tanh: 1 - 2/(e^{2x}+1). Safe at +/-inf. |err| ~1e-7.
__device__ __forceinline__ float fast_tanh(float x) {
    float e = __expf(2.0f * x);
    return 1.0f - 2.0f / (e + 1.0f);
}
// Workgroup barrier ordering LDS only — does NOT drain vmcnt, so global
// loads issued before it stay in flight across it.
__device__ __forceinline__ void bar_lds() {
    asm volatile("s_waitcnt lgkmcnt(0)\n\ts_barrier" ::: "memory");
}

// ---------------- fused precompute: weights -> MFMA B-frag layout, hi/lo fp16 ----
// F layout: [plane][nt][kc][lane(64)][j(8)]; value = W[n*K+k], n=nt*16+(l&15), k=kc*32+(l>>4)*8+j
__global__ __launch_bounds__(256) void pk_all(
    const float* __restrict__ Wvf1, const float* __restrict__ Wvf2,
    const float* __restrict__ Wm,   const float* __restrict__ bm,
    const float* __restrict__ logsig,
    _Float16* __restrict__ W1F, _Float16* __restrict__ W2F,
    _Float16* __restrict__ A3F, float* __restrict__ c_all)
{
    __shared__ float ls[32][62];
    const int b = blockIdx.x, t = threadIdx.x;
    if (b < 128) {                      // W1: N=256 x K=128 (16 nt, 4 kc)
        int u = b * 256 + t;            // 32768 per plane
        int j = u & 7, l = (u >> 3) & 63;
        int kc = (u >> 9) & 3, nt = (u >> 9) >> 2;
        int n = nt * 16 + (l & 15), k = kc * 32 + (l >> 4) * 8 + j;
        float w = Wvf1[n * 128 + k];
        _Float16 hi = (_Float16)w;
        W1F[u] = hi;
        W1F[32768 + u] = (_Float16)(w - (float)hi);
    } else if (b < 384) {               // W2: 256x256 (16 nt, 8 kc)
        int u = (b - 128) * 256 + t;    // 65536 per plane
        int j = u & 7, l = (u >> 3) & 63;
        int kc = (u >> 9) & 7, nt = (u >> 9) >> 3;
        int n = nt * 16 + (l & 15), k = kc * 32 + (l >> 4) * 8 + j;
        float w = Wvf2[n * 256 + k];
        _Float16 hi = (_Float16)w;
        W2F[u] = hi;
        W2F[65536 + u] = (_Float16)(w - (float)hi);
    } else if (b < 512) {               // A_r[h,v] = sum_l Wm[(h*62+l)*256+v]*logsig[r,1+l]
        for (int e = t; e < 32 * 62; e += 256)
            ls[e / 62][e % 62] = logsig[(e / 62) * 63 + 1 + (e % 62)];
        __syncthreads();
        int u = (b - 384) * 256 + t;    // 32768 per plane per r (8 nt, 8 kc)
        int j = u & 7, l = (u >> 3) & 63, kc = (u >> 9) & 7, nt = (u >> 12) & 7;
        int h = nt * 16 + (l & 15);
        int v = kc * 32 + (l >> 4) * 8 + j;
        float acc[32];
#pragma unroll
        for (int r = 0; r < 32; r++) acc[r] = 0.f;
        for (int ll = 0; ll < 62; ll++) {
            float wv = Wm[(h * 62 + ll) * 256 + v];
#pragma unroll
            for (int r = 0; r < 32; r++) acc[r] += wv * ls[r][ll];
        }
        for (int r = 0; r < 32; r++) {
            _Float16 hi = (_Float16)acc[r];
            A3F[r * 65536 + u] = hi;
            A3F[r * 65536 + 32768 + u] = (_Float16)(acc[r] - (float)hi);
        }
    } else {                            // c_r[h] = bm[h,:] . seg_r
        int u = (b - 512) * 256 + t;    // 4096 = [r(32)][h(128)]
        int r = u >> 7, h = u & 127;
        float acc = 0.f;
        for (int ll = 0; ll < 62; ll++) acc += bm[h * 62 + ll] * logsig[r * 63 + 1 + ll];
        c_all[u] = acc;
    }
}

// ---------------- main fused kernel: 32 blocks x 16 rows, 8 waves, 20-step Heun ---
// fp16 hi/lo on BOTH weights and activations, 3-chain product (ah*bh + ah*bl +
// al*bh; dropped al*bl ~2^-22). Weights STREAM from L2 in <=64-VGPR windows
// issued ahead of use (bar_lds doesn't drain vmcnt). LDS = hi/lo ping-pong act
// buffers (3 barriers/eval). Peak live regs ~185 -> no spill by construction.
__global__ __launch_bounds__(512, 2) void rde_main(
    const float* __restrict__ ts, const float* __restrict__ x0,
    const float* __restrict__ intervals,
    const float* __restrict__ b1g, const float* __restrict__ b2g,
    const float* __restrict__ Win, const float* __restrict__ bin,
    const float* __restrict__ Wout, const float* __restrict__ bout,
    const _Float16* __restrict__ W1F, const _Float16* __restrict__ W2F,
    const _Float16* __restrict__ A3F, const float* __restrict__ c_all,
    float* __restrict__ out)
{
    __shared__ __align__(16) _Float16 P0h[16 * AW], P0l[16 * AW];
    __shared__ __align__(16) _Float16 P1h[16 * AW], P1l[16 * AW];
    __shared__ float ivl[33];
    __shared__ int   r_arr[40];
    __shared__ float s_arr[40];
    __shared__ float lg[16][12];

    const int t    = threadIdx.x;
    const int lane = t & 63;
    const int wv   = t >> 6;        // wave 0..7
    const int m16  = lane & 15;
    const int q    = lane >> 4;
    const int row0 = blockIdx.x * 16;

    if (t < 33) ivl[t] = intervals[t];
    __syncthreads();

    const float ts0 = ts[0];
    const float dt  = __fdiv_rn(ts[32] - ts0, 20.0f);   // bit-exact vs reference

    if (t < 40) {   // searchsorted idx + 1/delta for all 40 VF evals
        int i = t >> 1;
        float tv = ts0 + (float)i * dt;
        if (t & 1) tv += dt;
        int p = 0;
        for (int j2 = 0; j2 < 32; j2++) p += (ivl[1 + j2] < tv) ? 1 : 0;
        int idx = p + 1;
        idx = idx < 1 ? 1 : idx;
        idx = idx > 32 ? 32 : idx;
        r_arr[t] = idx - 1;
        s_arr[t] = __fdiv_rn(1.0f, ivl[idx] - ivl[idx - 1]);
    }

    // biases preloaded (stage1/2 n-tiles: wv*2, wv*2+1)
    float b1v[2], b2v[2];
#pragma unroll
    for (int tt = 0; tt < 2; tt++) {
        b1v[tt] = b1g[(wv * 2 + tt) * 16 + m16];
        b2v[tt] = b2g[(wv * 2 + tt) * 16 + m16];
    }

    // y0 = x0 @ Win.T + bin -> Y regs (stage3 C/D layout: rows q*4+r, col wv*16+m16)
    float Y[4], K1[4];
#pragma unroll
    for (int r = 0; r < 4; r++) {
        int m = q * 4 + r, h = wv * 16 + m16;
        float acc = bin[h];
        const float* xr = x0 + (row0 + m) * 5;
#pragma unroll
        for (int d = 0; d < 5; d++) acc += xr[d] * Win[h * 5 + d];
        Y[r] = acc;
        K1[r] = 0.f;
        _Float16 hi = (_Float16)acc;
        P0h[m * AW + h] = hi;                   // 512 thr x 4 = full 16x128 coverage
        P0l[m * AW + h] = (_Float16)(acc - (float)hi);
    }
    __syncthreads();

    // W1 fragment prefetch for eval 0: [tt][kc][plane] = 64 VGPRs
    f16x8 w1f[2][4][2];
#pragma unroll
    for (int tt = 0; tt < 2; tt++)
#pragma unroll
        for (int kc = 0; kc < 4; kc++) {
            const _Float16* bp = W1F + (((wv * 2 + tt) * 4 + kc) * 64 + lane) * 8;
            w1f[tt][kc][0] = *(const f16x8*)bp;
            w1f[tt][kc][1] = *(const f16x8*)(bp + 32768);
        }

    _Float16 *Aih = P0h, *Ail = P0l;    // in buffers
    _Float16 *Aoh = P1h, *Aol = P1l;    // out buffers

#pragma unroll 1
    for (int e = 0; e < 40; e++) {
        const int half = e & 1;
        const int ri   = r_arr[e];
        const float s  = s_arr[e];
        const float cv = c_all[ri * 128 + wv * 16 + m16];
        const _Float16* ABase = A3F + ri * 65536;

        // ---- stage1: h1 = relu(y @ W1.T + b1), K=128; W1 frags preloaded ----
        // issue W2 window A (kc 0..3) first — in flight across all of stage1
        f16x8 w2a[2][4][2];
#pragma unroll
        for (int tt = 0; tt < 2; tt++)
#pragma unroll
            for (int kc = 0; kc < 4; kc++) {
                const _Float16* bp = W2F + (((wv * 2 + tt) * 8 + kc) * 64 + lane) * 8;
                w2a[tt][kc][0] = *(const f16x8*)bp;
                w2a[tt][kc][1] = *(const f16x8*)(bp + 65536);
            }
        f32x4 aA[2], aB[2], aC[2];
#pragma unroll
        for (int tt = 0; tt < 2; tt++) {
            aA[tt] = (f32x4){b1v[tt], b1v[tt], b1v[tt], b1v[tt]};
            aB[tt] = (f32x4){0.f, 0.f, 0.f, 0.f};
            aC[tt] = (f32x4){0.f, 0.f, 0.f, 0.f};
        }
#pragma unroll
        for (int kc = 0; kc < 4; kc++) {
            int ao = m16 * AW + kc * 32 + q * 8;
            f16x8 ah = *(const f16x8*)(Aih + ao);
            f16x8 al = *(const f16x8*)(Ail + ao);
#pragma unroll
            for (int tt = 0; tt < 2; tt++) {
                aA[tt] = __builtin_amdgcn_mfma_f32_16x16x32_f16(ah, w1f[tt][kc][0], aA[tt], 0, 0, 0);
                aB[tt] = __builtin_amdgcn_mfma_f32_16x16x32_f16(ah, w1f[tt][kc][1], aB[tt], 0, 0, 0);
                aC[tt] = __builtin_amdgcn_mfma_f32_16x16x32_f16(al, w1f[tt][kc][0], aC[tt], 0, 0, 0);
            }
        }
#pragma unroll
        for (int tt = 0; tt < 2; tt++) {        // commit h1 -> out (hi/lo)
            int n = (wv * 2 + tt) * 16 + m16;
#pragma unroll
            for (int r = 0; r < 4; r++) {       // C/D: col=lane&15, row=(lane>>4)*4+reg
                float v = fmaxf(aA[tt][r] + aB[tt][r] + aC[tt][r], 0.f);
                _Float16 hi = (_Float16)v;
                Aoh[(q * 4 + r) * AW + n] = hi;
                Aol[(q * 4 + r) * AW + n] = (_Float16)(v - (float)hi);
            }
        }
        bar_lds();

        // ---- stage2: h2 = tanh(h1 @ W2.T + b2), K=256 ----
#pragma unroll
        for (int tt = 0; tt < 2; tt++) {
            aA[tt] = (f32x4){b2v[tt], b2v[tt], b2v[tt], b2v[tt]};
            aB[tt] = (f32x4){0.f, 0.f, 0.f, 0.f};
            aC[tt] = (f32x4){0.f, 0.f, 0.f, 0.f};
        }
#pragma unroll
        for (int kc = 0; kc < 4; kc++) {        // first half with window A
            int ao = m16 * AW + kc * 32 + q * 8;
            f16x8 ah = *(const f16x8*)(Aoh + ao);
            f16x8 al = *(const f16x8*)(Aol + ao);
#pragma unroll
            for (int tt = 0; tt < 2; tt++) {
                aA[tt] = __builtin_amdgcn_mfma_f32_16x16x32_f16(ah, w2a[tt][kc][0], aA[tt], 0, 0, 0);
                aB[tt] = __builtin_amdgcn_mfma_f32_16x16x32_f16(ah, w2a[tt][kc][1], aB[tt], 0, 0, 0);
                aC[tt] = __builtin_amdgcn_mfma_f32_16x16x32_f16(al, w2a[tt][kc][0], aC[tt], 0, 0, 0);
            }
        }
        // window B (kc 4..7) — issued while first half computes is too late to
        // fully hide; issue here, ~150cyc ahead of first use
        f16x8 w2b[2][4][2];
#pragma unroll
        for (int tt = 0; tt < 2; tt++)
#pragma unroll
            for (int kc = 0; kc < 4; kc++) {
                const _Float16* bp = W2F + (((wv * 2 + tt) * 8 + 4 + kc) * 64 + lane) * 8;
                w2b[tt][kc][0] = *(const f16x8*)bp;
                w2b[tt][kc][1] = *(const f16x8*)(bp + 65536);
            }
#pragma unroll
        for (int kc = 0; kc < 4; kc++) {        // second half with window B
            int ao = m16 * AW + (4 + kc) * 32 + q * 8;
            f16x8 ah = *(const f16x8*)(Aoh + ao);
            f16x8 al = *(const f16x8*)(Aol + ao);
#pragma unroll
            for (int tt = 0; tt < 2; tt++) {
                aA[tt] = __builtin_amdgcn_mfma_f32_16x16x32_f16(ah, w2b[tt][kc][0], aA[tt], 0, 0, 0);
                aB[tt] = __builtin_amdgcn_mfma_f32_16x16x32_f16(ah, w2b[tt][kc][1], aB[tt], 0, 0, 0);
                aC[tt] = __builtin_amdgcn_mfma_f32_16x16x32_f16(al, w2b[tt][kc][0], aC[tt], 0, 0, 0);
            }
        }
        // issue A_r window A (stage3 n-tile = wv)
        f16x8 a3a[4][2];
#pragma unroll
        for (int kc = 0; kc < 4; kc++) {
            const _Float16* bp = ABase + ((wv * 8 + kc) * 64 + lane) * 8;
            a3a[kc][0] = *(const f16x8*)bp;
            a3a[kc][1] = *(const f16x8*)(bp + 32768);
        }
#pragma unroll
        for (int tt = 0; tt < 2; tt++) {        // commit h2 -> in (hi/lo)
            int n = (wv * 2 + tt) * 16 + m16;
#pragma unroll
            for (int r = 0; r < 4; r++) {
                float v = fast_tanh(aA[tt][r] + aB[tt][r] + aC[tt][r]);
                _Float16 hi = (_Float16)v;
                Aih[(q * 4 + r) * AW + n] = hi;
                Ail[(q * 4 + r) * AW + n] = (_Float16)(v - (float)hi);
            }
        }
        bar_lds();

        // ---- stage3: k = (h2 @ A_r.T + c_r) * s; winB + next-eval W1 issued here ----
        f16x8 a3b[4][2];
#pragma unroll
        for (int kc = 0; kc < 4; kc++) {
            const _Float16* bp = ABase + ((wv * 8 + 4 + kc) * 64 + lane) * 8;
            a3b[kc][0] = *(const f16x8*)bp;
            a3b[kc][1] = *(const f16x8*)(bp + 32768);
        }
#pragma unroll
        for (int tt = 0; tt < 2; tt++)          // next-eval W1 prefetch (fully hidden)
#pragma unroll
            for (int kc = 0; kc < 4; kc++) {
                const _Float16* bp = W1F + (((wv * 2 + tt) * 4 + kc) * 64 + lane) * 8;
                w1f[tt][kc][0] = *(const f16x8*)bp;
                w1f[tt][kc][1] = *(const f16x8*)(bp + 32768);
            }
        f32x4 kA = (f32x4){cv, cv, cv, cv};
        f32x4 kB = (f32x4){0.f, 0.f, 0.f, 0.f};
        f32x4 kC = (f32x4){0.f, 0.f, 0.f, 0.f};
#pragma unroll
        for (int kc = 0; kc < 4; kc++) {
            int ao = m16 * AW + kc * 32 + q * 8;
            f16x8 ah = *(const f16x8*)(Aih + ao);
            f16x8 al = *(const f16x8*)(Ail + ao);
            kA = __builtin_amdgcn_mfma_f32_16x16x32_f16(ah, a3a[kc][0], kA, 0, 0, 0);
            kB = __builtin_amdgcn_mfma_f32_16x16x32_f16(ah, a3a[kc][1], kB, 0, 0, 0);
            kC = __builtin_amdgcn_mfma_f32_16x16x32_f16(al, a3a[kc][0], kC, 0, 0, 0);
        }
#pragma unroll
        for (int kc = 0; kc < 4; kc++) {
            int ao = m16 * AW + (4 + kc) * 32 + q * 8;
            f16x8 ah = *(const f16x8*)(Aih + ao);
            f16x8 al = *(const f16x8*)(Ail + ao);
            kA = __builtin_amdgcn_mfma_f32_16x16x32_f16(ah, a3b[kc][0], kA, 0, 0, 0);
            kB = __builtin_amdgcn_mfma_f32_16x16x32_f16(ah, a3b[kc][1], kB, 0, 0, 0);
            kC = __builtin_amdgcn_mfma_f32_16x16x32_f16(al, a3b[kc][0], kC, 0, 0, 0);
        }
        {                                       // Heun commit + y -> out (hi/lo)
            int n = wv * 16 + m16;
#pragma unroll
            for (int r = 0; r < 4; r++) {
                float kv = (kA[r] + kB[r] + kC[r]) * s;
                float yn;
                if (half == 0) {                 // k1: stash, form y+dt*k1
                    K1[r] = kv;
                    yn = Y[r] + dt * kv;
                } else {                         // k2: y += 0.5*dt*(k1+k2)
                    yn = Y[r] + 0.5f * dt * (K1[r] + kv);
                    Y[r] = yn;
                }
                _Float16 hi = (_Float16)yn;
                Aoh[(q * 4 + r) * AW + n] = hi;
                Aol[(q * 4 + r) * AW + n] = (_Float16)(yn - (float)hi);
            }
        }
        bar_lds();
        _Float16* tp;
        tp = Aih; Aih = Aoh; Aoh = tp;
        tp = Ail; Ail = Aol; Aol = tp;
    }

    // epilogue: Y regs -> LDS floats (reuse P0h: 16 x 132 f32 = 8448 B, exact fit)
    float* Ys = (float*)P0h;
#pragma unroll
    for (int r = 0; r < 4; r++)
        Ys[(q * 4 + r) * 132 + wv * 16 + m16] = Y[r];
    __syncthreads();
    if (t < 160) {                  // logits
        int m = t / 10, c = t % 10;
        float acc = bout[c];
        for (int k = 0; k < 128; k++) acc += Ys[m * 132 + k] * Wout[c * 128 + k];
        lg[m][c] = acc;
    }
    __syncthreads();
    if (t < 16) {                   // softmax
        float mx = -1e30f;
#pragma unroll
        for (int c = 0; c < 10; c++) mx = fmaxf(mx, lg[t][c]);
        float ex[10], sum = 0.f;
#pragma unroll
        for (int c = 0; c < 10; c++) { ex[c] = expf(lg[t][c] - mx); sum += ex[c]; }
        float inv = __fdiv_rn(1.0f, sum);
#pragma unroll
        for (int c = 0; c < 10; c++) out[(row0 + t) * 10 + c] = ex[c] * inv;
    }
}

extern "C" void kernel_launch(void* const* d_in, const int* in_sizes, int n_in,
                              void* d_out, int out_size, void* d_ws, size_t ws_size,
                              hipStream_t stream) {
    const float* ts     = (const float*)d_in[0];
    const float* logsig = (const float*)d_in[1];
    const float* x0     = (const float*)d_in[2];
    const float* ivls   = (const float*)d_in[3];
    const float* Wvf1   = (const float*)d_in[4];
    const float* bvf1   = (const float*)d_in[5];
    const float* Wvf2   = (const float*)d_in[6];
    const float* bvf2   = (const float*)d_in[7];
    const float* Wm     = (const float*)d_in[8];
    const float* bm     = (const float*)d_in[9];
    const float* Win    = (const float*)d_in[10];
    const float* bin    = (const float*)d_in[11];
    const float* Wout   = (const float*)d_in[12];
    const float* bout   = (const float*)d_in[13];

    _Float16* W1F = (_Float16*)d_ws;            // 65536 halfs (128KB, hi+lo)
    _Float16* W2F = W1F + 65536;                // 131072 halfs (256KB, hi+lo)
    _Float16* A3F = W2F + 131072;               // 32*65536 halfs (4MB, hi+lo per r)
    float* c_all = (float*)(A3F + 32 * 65536);  // 4096 f32 (16KB)
    float* out = (float*)d_out;

    pk_all<<<dim3(528), dim3(256), 0, stream>>>(Wvf1, Wvf2, Wm, bm, logsig,
                                                W1F, W2F, A3F, c_all);
    rde_main<<<dim3(32), dim3(512), 0, stream>>>(
        ts, x0, ivls, bvf1, bvf2, Win, bin, Wout, bout,
        W1F, W2F, A3F, c_all, out);
}